// Round 1
// baseline (144.612 us; speedup 1.0000x reference)
//
#include <hip/hip_runtime.h>

// SpaceCarverGridSampler: nearest grid-sample with 3x3 hole-fix search.
// depth: (B=8, C=1, H=512, W=512) f32, grid: (B, 1024, 1024, 2) f32
// out:   (B, 1, 1024, 1024) f32
//
// Reference semantics:
//   x = (gx + 1) * 0.5 * (W-1); y = (gy + 1) * 0.5 * (H-1)   [align_corners=True]
//   ix = round_half_even(x); iy = round_half_even(y)          [jnp.round == RNE]
//   candidates: (0,0) first, then (dy,dx) row-major ring of radius 1
//   first candidate that is in-bounds AND value != 0.0 wins; else 0.0

#define SC_B  8
#define SC_H  512
#define SC_W  512
#define SC_HO 1024
#define SC_WO 1024

__global__ __launch_bounds__(256) void SpaceCarverGridSamplerModule_kernel(
    const float* __restrict__ depth,
    const float* __restrict__ grid,
    float* __restrict__ out,
    int total)
{
    int idx = blockIdx.x * blockDim.x + threadIdx.x;
    if (idx >= total) return;

    // npix = HO*WO = 1<<20; batch index
    int b = idx >> 20;

    // coalesced 8B grid load
    float2 g = reinterpret_cast<const float2*>(grid)[idx];

    // unnormalize, align_corners=True, exact fp32 order as reference
    float x = (g.x + 1.0f) * 0.5f * (float)(SC_W - 1);
    float y = (g.y + 1.0f) * 0.5f * (float)(SC_H - 1);

    // jnp.round = round-half-to-even = rintf under default RNE mode
    int ix = (int)rintf(x);
    int iy = (int)rintf(y);

    const float* __restrict__ img = depth + (size_t)b * (SC_H * SC_W);

    // center first, then ring in row-major (dy,dx) order
    const int dys[9] = { 0, -1, -1, -1,  0, 0,  1, 1, 1 };
    const int dxs[9] = { 0, -1,  0,  1, -1, 1, -1, 0, 1 };

    float result = 0.0f;
    #pragma unroll
    for (int k = 0; k < 9; ++k) {
        int cy = iy + dys[k];
        int cx = ix + dxs[k];
        if (cy >= 0 && cy < SC_H && cx >= 0 && cx < SC_W) {
            float v = img[cy * SC_W + cx];
            if (v != 0.0f) { result = v; break; }
        }
    }

    out[idx] = result;
}

extern "C" void kernel_launch(void* const* d_in, const int* in_sizes, int n_in,
                              void* d_out, int out_size, void* d_ws, size_t ws_size,
                              hipStream_t stream) {
    const float* depth = (const float*)d_in[0];  // (8,1,512,512)
    const float* grid  = (const float*)d_in[1];  // (8,1024,1024,2)
    float* out = (float*)d_out;                  // (8,1,1024,1024)

    int total = out_size;  // 8 * 1024 * 1024
    dim3 block(256);
    dim3 gridDim((total + block.x - 1) / block.x);
    SpaceCarverGridSamplerModule_kernel<<<gridDim, block, 0, stream>>>(depth, grid, out, total);
}